// Round 12
// baseline (40117.584 us; speedup 1.0000x reference)
//
#include <hip/hip_runtime.h>

using half8 = __attribute__((ext_vector_type(8))) _Float16;
using f32x4 = __attribute__((ext_vector_type(4))) float;
typedef unsigned long long u64;

static constexpr int TT  = 2048;   // time steps
static constexpr int NB  = 16;     // batch
static constexpr int SS  = 512;    // state dim
static constexpr int NWG = 8;      // cooperative scan workgroups (64 cols each)

__device__ __forceinline__ u64 tagpack(float f, unsigned tag) {
    return ((u64)tag << 32) | (u64)__float_as_uint(f);
}
__device__ __forceinline__ float tagval(u64 v) {
    return __uint_as_float((unsigned)(v & 0xFFFFFFFFu));
}

// -------------------- transpose + fp32->f16 (512x512): out[c][r] = in[r][c] --------------------
__global__ __launch_bounds__(256) void tcvt_kernel(const float* __restrict__ in,
                                                   _Float16* __restrict__ out) {
    __shared__ float tile[32][33];
    int bid = blockIdx.x;
    int rb = (bid >> 4) * 32, cb = (bid & 15) * 32;
    int tx = threadIdx.x & 31, ty = threadIdx.x >> 5;
    for (int rr = ty; rr < 32; rr += 8)
        tile[rr][tx] = in[(size_t)(rb + rr) * SS + cb + tx];
    __syncthreads();
    for (int rr = ty; rr < 32; rr += 8)
        out[(size_t)(cb + rr) * SS + rb + tx] = (_Float16)tile[tx][rr];
}

// -------------------- W = C0 @ B1 (512x512x512 fp32) --------------------
__global__ __launch_bounds__(256) void wmm_kernel(const float* __restrict__ C0,
                                                  const float* __restrict__ B1,
                                                  float* __restrict__ W) {
    int k = blockIdx.x;
    int tid = threadIdx.x;
    const float* crow = C0 + (size_t)k * SS;
    float s0 = 0.f, s1 = 0.f;
    for (int m = 0; m < SS; ++m) {
        float cv = crow[m];
        s0 += cv * B1[(size_t)m * SS + tid];
        s1 += cv * B1[(size_t)m * SS + tid + 256];
    }
    W[(size_t)k * SS + tid] = s0;
    W[(size_t)k * SS + tid + 256] = s1;
}

// -------------------- zero tagged stats mailbox (every launch: graph replay safe) ---------------
__global__ __launch_bounds__(512) void zinit_kernel(u64* __restrict__ p, int n) {
    int i = blockIdx.x * blockDim.x + threadIdx.x;
    if (i < n) p[i] = 0ull;
}

// -------------------- big GEMM: M=32768(b*2048+t), N=512, K=512 --------------------
template <int ALAY, int MODE>
__global__ __launch_bounds__(256) void gemm_kernel(const void* __restrict__ Aptr,
                                                   const _Float16* __restrict__ BT,
                                                   void* __restrict__ Outp) {
    int lane = threadIdx.x & 63;
    int wv   = threadIdx.x >> 6;
    int wid  = blockIdx.x * 4 + wv;
    int mt   = wid >> 3;
    int nb   = (wid & 7) * 64;
    int mbase = mt * 16;
    int lo = lane & 15, q = lane >> 4;

    f32x4 acc[4] = {{0,0,0,0},{0,0,0,0},{0,0,0,0},{0,0,0,0}};

    const float*    Af = (const float*)Aptr;
    const _Float16* Ah = (const _Float16*)Aptr;
    size_t arow = (size_t)(mbase + lo) * SS;

    #pragma unroll 2
    for (int kk = 0; kk < 16; ++kk) {
        int koff = kk * 32 + q * 8;
        half8 af;
        if (ALAY == 0) {
            const float* ar = Af + arow + koff;
            f32x4 a0 = *(const f32x4*)ar;
            f32x4 a1 = *(const f32x4*)(ar + 4);
            #pragma unroll
            for (int j = 0; j < 4; ++j) { af[j] = (_Float16)a0[j]; af[4 + j] = (_Float16)a1[j]; }
        } else {
            af = *(const half8*)(Ah + arow + koff);
        }
        #pragma unroll
        for (int j = 0; j < 4; ++j) {
            int n = nb + j * 16 + lo;
            half8 bf = *(const half8*)(BT + (size_t)n * SS + koff);
            acc[j] = __builtin_amdgcn_mfma_f32_16x16x32_f16(af, bf, acc[j], 0, 0, 0);
        }
    }

    #pragma unroll
    for (int j = 0; j < 4; ++j) {
        #pragma unroll
        for (int i = 0; i < 4; ++i) {
            int m = mbase + q * 4 + i;
            int n = nb + j * 16 + lo;
            if (MODE == 0) {
                ((_Float16*)Outp)[(size_t)m * SS + n] = (_Float16)acc[j][i];
            } else if (MODE == 1) {
                ((float*)Outp)[(size_t)m * SS + n] = acc[j][i];
            } else {
                int t2 = m & (TT - 1);
                int b2 = m >> 11;                 // T = 2048 = 2^11
                ((_Float16*)Outp)[((size_t)t2 * NB + b2) * SS + n] = (_Float16)acc[j][i];
            }
        }
    }
}

// -------------------- cooperative liquid scan: LDS weights + tagged-stats sync -----------------
// = round-11 kernel (LDS-resident weights, passing) with the flag+fence sync stage replaced by
// the round-8 hardware-verified tagged-stats protocol. Per step:
//   MFMA (weights from LDS) -> z -> ZW32 + wave LN partials -> B1
//   -> publish z (agent atomics) -> vmcnt(0) drain -> B2
//   -> wave0 publishes TAGGED stats {tag=t+1|f32}; a peer's tag proves its z was drained first
//   -> wave0 spins on 7 peers x 32 tagged words (<=4/lane) -> B3
//   -> all threads gather stats(16 u64) + z(8 u64 or LDS), replicated LN+GELU+h-update -> B5
// 3 serialized LLC RTs instead of 4 (no flag store, no release/acquire fences).
// ABA-safe: a WG reaches step t+2's z-overwrite only after seeing all peers' stats(t+1), which
// each peer publishes only after finishing its step-t z reads (program order). [round-8 proof]
__global__ __launch_bounds__(512) void scan13_kernel(
        const _Float16* __restrict__ U,     // [T][NB][SS]
        const float* __restrict__ Amat,     // [SS][SS] fp32 (k-major rows)
        const float* __restrict__ Kmat,     // [SS][SS]
        const float* __restrict__ ab,
        const float* __restrict__ gn,
        const float* __restrict__ bt,
        _Float16* __restrict__ hs,          // [NB][T][SS] history out
        u64*      __restrict__ zmail,       // [2][NWG][512] u64 == [2][NWG][16][64] f32
        u64*      __restrict__ smail,       // [2][16][NWG][2] u64 tagged (S1,S2)
        unsigned  tagbase)
{
    const int wg   = blockIdx.x;
    const int tid  = threadIdx.x;
    const int wv   = tid >> 6;
    const int lane = tid & 63;
    const int q    = lane >> 4;
    const int r    = lane & 15;

    __shared__ half8    WL[2][64][64];          // 128 KB: [A/K][col][granule] 16B frags, swizzled
    __shared__ _Float16 H16[16][520];           // f16 H for MFMA A-frags
    alignas(16) __shared__ float ZW32[16][64];  // own z slice staging (fp32)
    __shared__ float    STAT[4][16][2];         // per-MFMA-wave partial (S1,S2) per batch
    __shared__ float    GG[512];
    __shared__ float    BB[512];

    const int ub = tid & 15;            // h-update batch
    const int ug = tid >> 4;            // 0..31
    const int uc = ug * 16;             // h-update col start (slice index uc>>6 == wv)

    for (int e = tid; e < 16 * 520; e += 512) (&H16[0][0])[e] = (_Float16)0.f;
    GG[tid] = gn[tid];
    BB[tid] = bt[tid];

    // one-time weight preload into LDS (same (f16) rounding as all passing versions).
    // logical granule lg = ks*4+q covers k-range [lg*8, lg*8+8); stored at phys g = lg ^ (c&7).
    for (int f = tid; f < 8192; f += 512) {
        const int m  = f >> 12;          // 0 = A, 1 = K
        const int c  = (f >> 6) & 63;    // col within WG slice
        const int lg = f & 63;           // logical granule
        const float* src = m ? Kmat : Amat;
        half8 v;
        #pragma unroll
        for (int jj = 0; jj < 8; ++jj)
            v[jj] = (_Float16)src[(size_t)(lg * 8 + jj) * SS + wg * 64 + c];
        WL[m][c][lg ^ (c & 7)] = v;
    }

    const bool mf = (wv < 4);
    const int ccol = wg * 64 + (wv & 3) * 16 + r;
    const float abreg = ab[ccol];

    float hreg[16];                     // fp32 H master (batch ub, cols uc..uc+15)
    #pragma unroll
    for (int i = 0; i < 16; ++i) hreg[i] = 0.f;

    float uprev[4] = {0.f, 0.f, 0.f, 0.f};
    float ucur[4]  = {0.f, 0.f, 0.f, 0.f};
    if (mf) {
        #pragma unroll
        for (int i = 0; i < 4; ++i)
            ucur[i] = (float)U[(size_t)(q * 4 + i) * SS + ccol];   // t = 0
    }
    __syncthreads();

    for (int t = 0; t < TT; ++t) {
        const int par = t & 1;
        const unsigned want = tagbase + (unsigned)t + 1u;

        if (mf) {
            const int cc = (wv & 3) * 16 + r;
            f32x4 zA = {0.f, 0.f, 0.f, 0.f}, zK = {0.f, 0.f, 0.f, 0.f};
            #pragma unroll
            for (int ks = 0; ks < 16; ++ks) {
                half8 hf = *(const half8*)(&H16[r][ks * 32 + q * 8]);
                const int g = (ks * 4 + q) ^ (r & 7);
                zA = __builtin_amdgcn_mfma_f32_16x16x32_f16(hf, WL[0][cc][g], zA, 0, 0, 0);
                zK = __builtin_amdgcn_mfma_f32_16x16x32_f16(hf, WL[1][cc][g], zK, 0, 0, 0);
            }

            float z[4];
            #pragma unroll
            for (int i = 0; i < 4; ++i) {
                z[i] = zA[i] + ucur[i] + abreg + zK[i] * uprev[i];
                uprev[i] = ucur[i];
                ZW32[q * 4 + i][(wv & 3) * 16 + r] = z[i];   // fp32 LDS transpose stage
            }

            // per-tile LN moments (fp32): reduce over 16 cols (r bits)
            float s1[4], s2[4];
            #pragma unroll
            for (int i = 0; i < 4; ++i) { s1[i] = z[i]; s2[i] = z[i] * z[i]; }
            #pragma unroll
            for (int off = 1; off < 16; off <<= 1) {
                #pragma unroll
                for (int i = 0; i < 4; ++i) {
                    s1[i] += __shfl_xor(s1[i], off, 64);
                    s2[i] += __shfl_xor(s2[i], off, 64);
                }
            }
            if (r == 0) {
                #pragma unroll
                for (int i = 0; i < 4; ++i) {
                    STAT[wv][q * 4 + i][0] = s1[i];
                    STAT[wv][q * 4 + i][1] = s2[i];
                }
            }
        }
        __syncthreads();                                   // B1: ZW32/STAT ready

        // publish z slice: 512 threads x one contiguous 8B agent-scope atomic store (fp32 pairs)
        {
            u64 v = ((const u64*)ZW32)[tid];
            __hip_atomic_store(&zmail[((size_t)par * NWG + wg) * 512 + tid], v,
                               __ATOMIC_RELAXED, __HIP_MEMORY_SCOPE_AGENT);
        }
        // prefetch next-step U while the publish stores drain
        if (mf) {
            const int tn = (t + 1 < TT) ? (t + 1) : t;
            #pragma unroll
            for (int i = 0; i < 4; ++i)
                ucur[i] = (float)U[((size_t)tn * NB + (q * 4 + i)) * SS + ccol];
        }
        __builtin_amdgcn_s_waitcnt(0);
        __syncthreads();                                   // B2: all z at coherence point

        // wave0: publish TAGGED stats, then spin on 7 peers x 32 tagged words (<=4/lane)
        if (wv == 0) {
            if (lane < 16) {
                float S1 = STAT[0][lane][0] + STAT[1][lane][0] + STAT[2][lane][0] + STAT[3][lane][0];
                float S2 = STAT[0][lane][1] + STAT[1][lane][1] + STAT[2][lane][1] + STAT[3][lane][1];
                u64* sd = &smail[(((size_t)par * 16 + lane) * NWG + wg) * 2];
                __hip_atomic_store(sd + 0, tagpack(S1, want), __ATOMIC_RELAXED, __HIP_MEMORY_SCOPE_AGENT);
                __hip_atomic_store(sd + 1, tagpack(S2, want), __ATOMIC_RELAXED, __HIP_MEMORY_SCOPE_AGENT);
            }
            // flattened peer-word ids f in [0,224): peer p = 1 + f/32, rem = f%32,
            // batch = rem>>1, word j = rem&1. lane handles f = lane, lane+64, lane+128,
            // and (lane<32) f = lane+192.
            auto saddr = [&](int f) -> const u64* {
                const int p   = 1 + (f >> 5);
                const int rem = f & 31;
                return &smail[(((size_t)par * 16 + (rem >> 1)) * NWG + ((wg + p) & (NWG - 1))) * 2
                              + (rem & 1)];
            };
            const u64* a0 = saddr(lane);
            const u64* a1 = saddr(lane + 64);
            const u64* a2 = saddr(lane + 128);
            const u64* a3 = (lane < 32) ? saddr(lane + 192) : nullptr;
            for (;;) {
                unsigned t0 = (unsigned)(__hip_atomic_load(a0, __ATOMIC_RELAXED, __HIP_MEMORY_SCOPE_AGENT) >> 32);
                unsigned t1 = (unsigned)(__hip_atomic_load(a1, __ATOMIC_RELAXED, __HIP_MEMORY_SCOPE_AGENT) >> 32);
                unsigned t2 = (unsigned)(__hip_atomic_load(a2, __ATOMIC_RELAXED, __HIP_MEMORY_SCOPE_AGENT) >> 32);
                unsigned t3 = a3 ? (unsigned)(__hip_atomic_load(a3, __ATOMIC_RELAXED, __HIP_MEMORY_SCOPE_AGENT) >> 32)
                                 : want;
                if (t0 == want && t1 == want && t2 == want && t3 == want) break;
            }
        }
        __syncthreads();                                   // B3: all WGs' z+stats readable

        // gather this thread's 16 z values (batch ub, cols uc..uc+15), fp32
        float zz[16];
        if (wv == wg) {                                    // own slice: read LDS copy
            #pragma unroll
            for (int i = 0; i < 16; ++i) zz[i] = ZW32[ub][(uc & 63) + i];
        } else {
            union { u64 u[8]; float f[16]; } zu;
            const u64* src = &zmail[(((size_t)par * NWG + wv) * 16 + ub) * 32 + ((uc & 63) >> 1)];
            #pragma unroll
            for (int i = 0; i < 8; ++i)
                zu.u[i] = __hip_atomic_load(src + i, __ATOMIC_RELAXED, __HIP_MEMORY_SCOPE_AGENT);
            #pragma unroll
            for (int i = 0; i < 16; ++i) zz[i] = zu.f[i];
        }

        // per-thread global LN stats (fixed ascending WG order -> identical bits in every WG)
        float S1 = 0.f, S2 = 0.f;
        #pragma unroll
        for (int i = 0; i < NWG; ++i) {
            const u64* sp = &smail[(((size_t)par * 16 + ub) * NWG + i) * 2];
            u64 v0 = __hip_atomic_load(sp + 0, __ATOMIC_RELAXED, __HIP_MEMORY_SCOPE_AGENT);
            u64 v1 = __hip_atomic_load(sp + 1, __ATOMIC_RELAXED, __HIP_MEMORY_SCOPE_AGENT);
            S1 += tagval(v0); S2 += tagval(v1);
        }
        const float mu  = S1 * (1.0f / SS);
        const float var = S2 * (1.0f / SS) - mu * mu;
        const float rs  = rsqrtf(var + 1e-5f);

        // replicated LN + exact GELU + h update (16 elems/thread), identical in all WGs
        half8 hh0, hh1;
        #pragma unroll
        for (int i4 = 0; i4 < 4; ++i4) {
            f32x4 gq = *(const f32x4*)&GG[uc + i4 * 4];
            f32x4 bq = *(const f32x4*)&BB[uc + i4 * 4];
            #pragma unroll
            for (int jj = 0; jj < 4; ++jj) {
                const int e = i4 * 4 + jj;
                float zn = (zz[e] - mu) * rs * gq[jj] + bq[jj];
                float ge = 0.5f * zn * (1.0f + erff(zn * 0.70710678118654752f));
                hreg[e] += ge;
                if (e < 8) hh0[e] = (_Float16)hreg[e]; else hh1[e - 8] = (_Float16)hreg[e];
            }
        }
        *(half8*)(&H16[ub][uc])     = hh0;
        *(half8*)(&H16[ub][uc + 8]) = hh1;
        if (wv == wg) {   // slice owner writes history
            _Float16* hd = hs + ((size_t)ub * TT + t) * SS + uc;
            *(half8*)(hd)     = hh0;
            *(half8*)(hd + 8) = hh1;
        }
        __syncthreads();                                   // B5: H16/ZW32/STAT free for next step
    }
}

// -------------------- host launch --------------------
extern "C" void kernel_launch(void* const* d_in, const int* in_sizes, int n_in,
                              void* d_out, int out_size, void* d_ws, size_t ws_size,
                              hipStream_t stream) {
    const float* x   = (const float*)d_in[0];
    const float* A0  = (const float*)d_in[1];
    const float* B0  = (const float*)d_in[2];
    const float* C0  = (const float*)d_in[3];
    const float* K0  = (const float*)d_in[4];
    const float* ab0 = (const float*)d_in[5];
    const float* g0  = (const float*)d_in[6];
    const float* bt0 = (const float*)d_in[7];
    const float* A1  = (const float*)d_in[8];
    const float* B1  = (const float*)d_in[9];
    const float* C1  = (const float*)d_in[10];
    const float* K1  = (const float*)d_in[11];
    const float* ab1 = (const float*)d_in[12];
    const float* g1  = (const float*)d_in[13];
    const float* bt1 = (const float*)d_in[14];

    char* ws = (char*)d_ws;
    size_t off = 0;
    auto alloc = [&](size_t bytes) { size_t o = off; off = (off + bytes + 255) & ~(size_t)255; return o; };

    const size_t BUF_BYTES = (size_t)NB * TT * SS * 2;   // 33.5 MB f16
    const size_t WP_BYTES  = (size_t)SS * SS * 2;        // 512 KB f16

    _Float16* U0  = (_Float16*)(ws + alloc(BUF_BYTES));  // [t][b][c]
    _Float16* U1  = (_Float16*)(ws + alloc(BUF_BYTES));  // [t][b][c]
    _Float16* hs0 = (_Float16*)(ws + alloc(BUF_BYTES));  // [b][t][c]
    _Float16* hs1 = (_Float16*)(ws + alloc(BUF_BYTES));  // [b][t][c]
    _Float16* B0T = (_Float16*)(ws + alloc(WP_BYTES));
    _Float16* WT  = (_Float16*)(ws + alloc(WP_BYTES));
    _Float16* C1T = (_Float16*)(ws + alloc(WP_BYTES));
    float*    Wf  = (float*)(ws + alloc((size_t)SS * SS * 4));
    u64*      zmail = (u64*)(ws + alloc((size_t)2 * NWG * 512 * 8));    // 64 KB
    u64*      smail = (u64*)(ws + alloc((size_t)2 * 16 * NWG * 2 * 8)); // 4 KB tagged stats

    const int SN = 2 * 16 * NWG * 2;   // 512 u64

    // zero tagged stats mailbox (stream-ordered; graph-replay safe). Tags then rise 1..2*TT.
    zinit_kernel<<<1, 512, 0, stream>>>(smail, SN);

    // weight preps
    tcvt_kernel<<<256, 256, 0, stream>>>(B0, B0T);
    tcvt_kernel<<<256, 256, 0, stream>>>(C1, C1T);
    wmm_kernel<<<512, 256, 0, stream>>>(C0, B1, Wf);     // W = C0 @ B1 (layer-fold)
    tcvt_kernel<<<256, 256, 0, stream>>>(Wf, WT);

    // U0 = x @ B0, scan layout [t][b][c]
    gemm_kernel<0, 2><<<4096, 256, 0, stream>>>((const void*)x, B0T, (void*)U0);

    // layer-0 cooperative scan (tags 1..TT)
    scan13_kernel<<<NWG, 512, 0, stream>>>(U0, A0, K0, ab0, g0, bt0, hs0, zmail, smail, 0u);

    // U1 = hs0 @ (C0@B1), scan layout
    gemm_kernel<1, 2><<<4096, 256, 0, stream>>>((const void*)hs0, WT, (void*)U1);

    // layer-1 cooperative scan (tags TT+1..2*TT)
    scan13_kernel<<<NWG, 512, 0, stream>>>(U1, A1, K1, ab1, g1, bt1, hs1, zmail, smail, (unsigned)TT);

    // out = hs1 @ C1 (fp32 [b][t][c])
    gemm_kernel<1, 1><<<4096, 256, 0, stream>>>((const void*)hs1, C1T, d_out);
}

// Round 13
// 19248.552 us; speedup vs baseline: 2.0842x; 2.0842x over previous
//
#include <hip/hip_runtime.h>

using half8 = __attribute__((ext_vector_type(8))) _Float16;
using f32x4 = __attribute__((ext_vector_type(4))) float;
typedef unsigned long long u64;

static constexpr int TT  = 2048;   // time steps
static constexpr int NB  = 16;     // batch
static constexpr int SS  = 512;    // state dim
static constexpr int NWG = 8;      // WGs per team (64 cols each)
static constexpr int NT  = 2;      // teams (8 batches each)
static constexpr int NBT = 8;      // batches per team

// -------------------- transpose + fp32->f16 (512x512): out[c][r] = in[r][c] --------------------
__global__ __launch_bounds__(256) void tcvt_kernel(const float* __restrict__ in,
                                                   _Float16* __restrict__ out) {
    __shared__ float tile[32][33];
    int bid = blockIdx.x;
    int rb = (bid >> 4) * 32, cb = (bid & 15) * 32;
    int tx = threadIdx.x & 31, ty = threadIdx.x >> 5;
    for (int rr = ty; rr < 32; rr += 8)
        tile[rr][tx] = in[(size_t)(rb + rr) * SS + cb + tx];
    __syncthreads();
    for (int rr = ty; rr < 32; rr += 8)
        out[(size_t)(cb + rr) * SS + rb + tx] = (_Float16)tile[tx][rr];
}

// -------------------- W = C0 @ B1 (512x512x512 fp32) --------------------
__global__ __launch_bounds__(256) void wmm_kernel(const float* __restrict__ C0,
                                                  const float* __restrict__ B1,
                                                  float* __restrict__ W) {
    int k = blockIdx.x;
    int tid = threadIdx.x;
    const float* crow = C0 + (size_t)k * SS;
    float s0 = 0.f, s1 = 0.f;
    for (int m = 0; m < SS; ++m) {
        float cv = crow[m];
        s0 += cv * B1[(size_t)m * SS + tid];
        s1 += cv * B1[(size_t)m * SS + tid + 256];
    }
    W[(size_t)k * SS + tid] = s0;
    W[(size_t)k * SS + tid + 256] = s1;
}

// -------------------- zero flags (every launch: graph replay safe) -----------------------------
__global__ __launch_bounds__(512) void zinit_kernel(unsigned* __restrict__ p, int n) {
    int i = blockIdx.x * blockDim.x + threadIdx.x;
    if (i < n) p[i] = 0u;
}

// -------------------- big GEMM: M=32768(b*2048+t), N=512, K=512 --------------------
template <int ALAY, int MODE>
__global__ __launch_bounds__(256) void gemm_kernel(const void* __restrict__ Aptr,
                                                   const _Float16* __restrict__ BT,
                                                   void* __restrict__ Outp) {
    int lane = threadIdx.x & 63;
    int wv   = threadIdx.x >> 6;
    int wid  = blockIdx.x * 4 + wv;
    int mt   = wid >> 3;
    int nb   = (wid & 7) * 64;
    int mbase = mt * 16;
    int lo = lane & 15, q = lane >> 4;

    f32x4 acc[4] = {{0,0,0,0},{0,0,0,0},{0,0,0,0},{0,0,0,0}};

    const float*    Af = (const float*)Aptr;
    const _Float16* Ah = (const _Float16*)Aptr;
    size_t arow = (size_t)(mbase + lo) * SS;

    #pragma unroll 2
    for (int kk = 0; kk < 16; ++kk) {
        int koff = kk * 32 + q * 8;
        half8 af;
        if (ALAY == 0) {
            const float* ar = Af + arow + koff;
            f32x4 a0 = *(const f32x4*)ar;
            f32x4 a1 = *(const f32x4*)(ar + 4);
            #pragma unroll
            for (int j = 0; j < 4; ++j) { af[j] = (_Float16)a0[j]; af[4 + j] = (_Float16)a1[j]; }
        } else {
            af = *(const half8*)(Ah + arow + koff);
        }
        #pragma unroll
        for (int j = 0; j < 4; ++j) {
            int n = nb + j * 16 + lo;
            half8 bf = *(const half8*)(BT + (size_t)n * SS + koff);
            acc[j] = __builtin_amdgcn_mfma_f32_16x16x32_f16(af, bf, acc[j], 0, 0, 0);
        }
    }

    #pragma unroll
    for (int j = 0; j < 4; ++j) {
        #pragma unroll
        for (int i = 0; i < 4; ++i) {
            int m = mbase + q * 4 + i;
            int n = nb + j * 16 + lo;
            if (MODE == 0) {
                ((_Float16*)Outp)[(size_t)m * SS + n] = (_Float16)acc[j][i];
            } else if (MODE == 1) {
                ((float*)Outp)[(size_t)m * SS + n] = acc[j][i];
            } else {
                int t2 = m & (TT - 1);
                int b2 = m >> 11;                 // T = 2048 = 2^11
                ((_Float16*)Outp)[((size_t)t2 * NB + b2) * SS + n] = (_Float16)acc[j][i];
            }
        }
    }
}

// -------------------- cooperative liquid scan: round-4 protocol, 2 teams x 8 batches -----------
// = the round-4 champion (scan5: publish z -> vmcnt(0)+barrier -> flag -> parallel 1-word poll ->
// gather), with (a) the redundant release/acquire fences removed (z is drained before the flag
// store; all mailbox reads are cache-bypassing agent atomics; __syncthreads is the compiler
// fence), and (b) the batch dim split into 2 independent teams of 8 WGs (zero inter-team
// coupling). MFMA uses 8 valid A-rows of 16 (rows 8-15 of H16 are zero). Per-batch LN stats
// keep the identical 8x64-col decomposition -> bit-identical numerics.
__global__ __launch_bounds__(512) void scan14_kernel(
        const _Float16* __restrict__ U,     // [T][NB][SS]
        const float* __restrict__ Amat,     // [SS][SS] fp32 (k-major rows)
        const float* __restrict__ Kmat,     // [SS][SS]
        const float* __restrict__ ab,
        const float* __restrict__ gn,
        const float* __restrict__ bt,
        _Float16* __restrict__ hs,          // [NB][T][SS] history out
        u64*      __restrict__ zmail,       // [NT][2][NWG][256] u64 == fp32 [8 batch][64 col]
        u64*      __restrict__ smail,       // [NT][2][NWG][8] u64 packed (S1,S2)
        unsigned* __restrict__ flags)       // [NT][NWG][32] monotone step counters
{
    const int team = blockIdx.x >> 3;
    const int wg   = blockIdx.x & (NWG - 1);
    const int bt0  = team * NBT;
    const int tid  = threadIdx.x;
    const int wv   = tid >> 6;
    const int lane = tid & 63;
    const int q    = lane >> 4;
    const int r    = lane & 15;

    u64*      zmailT = zmail + (size_t)team * 2 * NWG * 256;
    u64*      smailT = smail + (size_t)team * 2 * NWG * 8;
    unsigned* flagsT = flags + (size_t)team * NWG * 32;

    __shared__ _Float16 H16[16][520];           // rows 0-7 = team batches; rows 8-15 stay ZERO
    alignas(16) __shared__ float ZW32[8][64];   // own z slice staging (fp32)
    __shared__ float    STAT[4][16][2];         // per-MFMA-wave partial (S1,S2) (rows 8-15 junk)
    __shared__ float    GG[512];
    __shared__ float    BB[512];

    const int ub = tid & 7;             // batch within team
    const int ug = tid >> 3;            // 0..63
    const int uc = ug * 8;              // col start (8 cols/thread)
    const int ow = ug >> 3;             // owning WG of this col slice (0..7)

    for (int e = tid; e < 16 * 520; e += 512) (&H16[0][0])[e] = (_Float16)0.f;
    GG[tid] = gn[tid];
    BB[tid] = bt[tid];

    const bool mf = (wv < 4);
    const int ccol = wg * 64 + (wv & 3) * 16 + r;

    // weight slices (compiler streams from L2 per step; measured not on the critical path)
    half8 wA[16], wK[16];
    if (mf) {
        for (int ks = 0; ks < 16; ++ks) {
            half8 a, k;
            #pragma unroll
            for (int jj = 0; jj < 8; ++jj) {
                int kk = ks * 32 + q * 8 + jj;
                a[jj] = (_Float16)Amat[(size_t)kk * SS + ccol];
                k[jj] = (_Float16)Kmat[(size_t)kk * SS + ccol];
            }
            wA[ks] = a; wK[ks] = k;
        }
    }
    const float abreg = ab[ccol];
    float hreg[8];
    #pragma unroll
    for (int i = 0; i < 8; ++i) hreg[i] = 0.f;
    float uprev[4] = {0.f, 0.f, 0.f, 0.f};
    float ucur[4]  = {0.f, 0.f, 0.f, 0.f};
    if (mf && q < 2) {
        #pragma unroll
        for (int i = 0; i < 4; ++i)
            ucur[i] = (float)U[(size_t)(bt0 + q * 4 + i) * SS + ccol];   // t = 0
    }
    __syncthreads();

    for (int t = 0; t < TT; ++t) {
        const int par = t & 1;

        if (mf) {
            f32x4 zA = {0.f, 0.f, 0.f, 0.f}, zK = {0.f, 0.f, 0.f, 0.f};
            #pragma unroll
            for (int ks = 0; ks < 16; ++ks) {
                half8 hf = *(const half8*)(&H16[r][ks * 32 + q * 8]);
                zA = __builtin_amdgcn_mfma_f32_16x16x32_f16(hf, wA[ks], zA, 0, 0, 0);
                zK = __builtin_amdgcn_mfma_f32_16x16x32_f16(hf, wK[ks], zK, 0, 0, 0);
            }

            float z[4];
            #pragma unroll
            for (int i = 0; i < 4; ++i) {
                z[i] = zA[i] + ucur[i] + abreg + zK[i] * uprev[i];
                uprev[i] = ucur[i];
            }
            if (q < 2) {            // valid batches 0..7 only
                #pragma unroll
                for (int i = 0; i < 4; ++i)
                    ZW32[q * 4 + i][(wv & 3) * 16 + r] = z[i];
            }

            // per-tile LN moments (rows >=8 junk, never read)
            float s1[4], s2[4];
            #pragma unroll
            for (int i = 0; i < 4; ++i) { s1[i] = z[i]; s2[i] = z[i] * z[i]; }
            #pragma unroll
            for (int off = 1; off < 16; off <<= 1) {
                #pragma unroll
                for (int i = 0; i < 4; ++i) {
                    s1[i] += __shfl_xor(s1[i], off, 64);
                    s2[i] += __shfl_xor(s2[i], off, 64);
                }
            }
            if (r == 0) {
                #pragma unroll
                for (int i = 0; i < 4; ++i) {
                    STAT[wv][q * 4 + i][0] = s1[i];
                    STAT[wv][q * 4 + i][1] = s2[i];
                }
            }
        }
        __syncthreads();                                   // B1: ZW32/STAT ready

        // publish z slice: 256 threads x one contiguous 8B agent-scope atomic store
        if (tid < 256) {
            u64 v = ((const u64*)ZW32)[tid];
            __hip_atomic_store(&zmailT[((size_t)par * NWG + wg) * 256 + tid], v,
                               __ATOMIC_RELAXED, __HIP_MEMORY_SCOPE_AGENT);
        }
        // publish WG-partial LN moments
        if (wv == 0 && lane < NBT) {
            float S1 = STAT[0][lane][0] + STAT[1][lane][0] + STAT[2][lane][0] + STAT[3][lane][0];
            float S2 = STAT[0][lane][1] + STAT[1][lane][1] + STAT[2][lane][1] + STAT[3][lane][1];
            union { float f[2]; u64 u; } pk;
            pk.f[0] = S1; pk.f[1] = S2;
            __hip_atomic_store(&smailT[((size_t)par * NWG + wg) * 8 + lane], pk.u,
                               __ATOMIC_RELAXED, __HIP_MEMORY_SCOPE_AGENT);
        }
        // prefetch next-step U while the publish stores drain
        if (mf && q < 2) {
            const int tn = (t + 1 < TT) ? (t + 1) : t;
            #pragma unroll
            for (int i = 0; i < 4; ++i)
                ucur[i] = (float)U[((size_t)tn * NB + bt0 + q * 4 + i) * SS + ccol];
        }
        __builtin_amdgcn_s_waitcnt(0);
        __syncthreads();                                   // B2: all publishes at coherence point

        // flag publish + parallel 1-word-per-lane poll (fences removed: drain + barrier suffice,
        // and all mailbox reads are cache-bypassing agent atomics)
        if (tid == 0)
            __hip_atomic_store(&flagsT[wg * 32], (unsigned)(t + 1),
                               __ATOMIC_RELAXED, __HIP_MEMORY_SCOPE_AGENT);
        if (wv == 0 && lane >= 1 && lane < NWG) {
            unsigned* fp = &flagsT[((wg + lane) & (NWG - 1)) * 32];
            while (__hip_atomic_load(fp, __ATOMIC_RELAXED, __HIP_MEMORY_SCOPE_AGENT)
                   < (unsigned)(t + 1)) {}
        }
        __syncthreads();                                   // B3: all team WGs published step t

        // gather this thread's 8 z values (batch ub, cols uc..uc+7), fp32
        float zz[8];
        if (ow == wg) {
            #pragma unroll
            for (int i = 0; i < 8; ++i) zz[i] = ZW32[ub][(uc & 63) + i];
        } else {
            union { u64 u[4]; float f[8]; } zu;
            const u64* src = &zmailT[((size_t)par * NWG + ow) * 256 + ub * 32 + ((uc & 63) >> 1)];
            #pragma unroll
            for (int i = 0; i < 4; ++i)
                zu.u[i] = __hip_atomic_load(src + i, __ATOMIC_RELAXED, __HIP_MEMORY_SCOPE_AGENT);
            #pragma unroll
            for (int i = 0; i < 8; ++i) zz[i] = zu.f[i];
        }

        // per-thread global LN stats (fixed ascending WG order -> identical bits in every WG)
        float S1 = 0.f, S2 = 0.f;
        #pragma unroll
        for (int i = 0; i < NWG; ++i) {
            union { u64 u; float f[2]; } pk;
            pk.u = __hip_atomic_load(&smailT[((size_t)par * NWG + i) * 8 + ub],
                                     __ATOMIC_RELAXED, __HIP_MEMORY_SCOPE_AGENT);
            S1 += pk.f[0]; S2 += pk.f[1];
        }
        const float mu  = S1 * (1.0f / SS);
        const float var = S2 * (1.0f / SS) - mu * mu;
        const float rs  = rsqrtf(var + 1e-5f);

        // replicated LN + exact GELU + h update (8 elems/thread), identical in all team WGs
        half8 hh;
        #pragma unroll
        for (int i4 = 0; i4 < 2; ++i4) {
            f32x4 gq = *(const f32x4*)&GG[uc + i4 * 4];
            f32x4 bq = *(const f32x4*)&BB[uc + i4 * 4];
            #pragma unroll
            for (int jj = 0; jj < 4; ++jj) {
                const int e = i4 * 4 + jj;
                float zn = (zz[e] - mu) * rs * gq[jj] + bq[jj];
                float ge = 0.5f * zn * (1.0f + erff(zn * 0.70710678118654752f));
                hreg[e] += ge;
                hh[e] = (_Float16)hreg[e];
            }
        }
        *(half8*)(&H16[ub][uc]) = hh;
        if (ow == wg) {   // slice owner writes history
            *(half8*)(hs + ((size_t)(bt0 + ub) * TT + t) * SS + uc) = hh;
        }
        __syncthreads();                                   // B5: H16/ZW32/STAT free for next step
    }
}

// -------------------- host launch --------------------
extern "C" void kernel_launch(void* const* d_in, const int* in_sizes, int n_in,
                              void* d_out, int out_size, void* d_ws, size_t ws_size,
                              hipStream_t stream) {
    const float* x   = (const float*)d_in[0];
    const float* A0  = (const float*)d_in[1];
    const float* B0  = (const float*)d_in[2];
    const float* C0  = (const float*)d_in[3];
    const float* K0  = (const float*)d_in[4];
    const float* ab0 = (const float*)d_in[5];
    const float* g0  = (const float*)d_in[6];
    const float* bt0 = (const float*)d_in[7];
    const float* A1  = (const float*)d_in[8];
    const float* B1  = (const float*)d_in[9];
    const float* C1  = (const float*)d_in[10];
    const float* K1  = (const float*)d_in[11];
    const float* ab1 = (const float*)d_in[12];
    const float* g1  = (const float*)d_in[13];
    const float* bt1 = (const float*)d_in[14];

    char* ws = (char*)d_ws;
    size_t off = 0;
    auto alloc = [&](size_t bytes) { size_t o = off; off = (off + bytes + 255) & ~(size_t)255; return o; };

    const size_t BUF_BYTES = (size_t)NB * TT * SS * 2;   // 33.5 MB f16
    const size_t WP_BYTES  = (size_t)SS * SS * 2;        // 512 KB f16

    _Float16* U0  = (_Float16*)(ws + alloc(BUF_BYTES));  // [t][b][c]
    _Float16* U1  = (_Float16*)(ws + alloc(BUF_BYTES));  // [t][b][c]
    _Float16* hs0 = (_Float16*)(ws + alloc(BUF_BYTES));  // [b][t][c]
    _Float16* hs1 = (_Float16*)(ws + alloc(BUF_BYTES));  // [b][t][c]
    _Float16* B0T = (_Float16*)(ws + alloc(WP_BYTES));
    _Float16* WT  = (_Float16*)(ws + alloc(WP_BYTES));
    _Float16* C1T = (_Float16*)(ws + alloc(WP_BYTES));
    float*    Wf  = (float*)(ws + alloc((size_t)SS * SS * 4));
    u64*      zmail  = (u64*)(ws + alloc((size_t)NT * 2 * NWG * 256 * 8));  // 64 KB
    u64*      smail  = (u64*)(ws + alloc((size_t)NT * 2 * NWG * 8 * 8));    // 2 KB
    unsigned* flags0 = (unsigned*)(ws + alloc((size_t)NT * NWG * 32 * 4));  // layer 0
    unsigned* flags1 = (unsigned*)(ws + alloc((size_t)NT * NWG * 32 * 4));  // layer 1

    // zero both layers' flags (stream-ordered; graph-replay safe)
    zinit_kernel<<<2, 512, 0, stream>>>(flags0, 2 * NT * NWG * 32);
    (void)flags1;

    // weight preps
    tcvt_kernel<<<256, 256, 0, stream>>>(B0, B0T);
    tcvt_kernel<<<256, 256, 0, stream>>>(C1, C1T);
    wmm_kernel<<<512, 256, 0, stream>>>(C0, B1, Wf);     // W = C0 @ B1 (layer-fold)
    tcvt_kernel<<<256, 256, 0, stream>>>(Wf, WT);

    // U0 = x @ B0, scan layout [t][b][c]
    gemm_kernel<0, 2><<<4096, 256, 0, stream>>>((const void*)x, B0T, (void*)U0);

    // layer-0 cooperative scan (2 teams x 8 WGs)
    scan14_kernel<<<NT * NWG, 512, 0, stream>>>(U0, A0, K0, ab0, g0, bt0, hs0,
                                                zmail, smail, flags0);

    // U1 = hs0 @ (C0@B1), scan layout
    gemm_kernel<1, 2><<<4096, 256, 0, stream>>>((const void*)hs0, WT, (void*)U1);

    // layer-1 cooperative scan
    scan14_kernel<<<NT * NWG, 512, 0, stream>>>(U1, A1, K1, ab1, g1, bt1, hs1,
                                                zmail, smail, flags1);

    // out = hs1 @ C1 (fp32 [b][t][c])
    gemm_kernel<1, 1><<<4096, 256, 0, stream>>>((const void*)hs1, C1T, d_out);
}

// Round 15
// 14564.365 us; speedup vs baseline: 2.7545x; 1.3216x over previous
//
#include <hip/hip_runtime.h>

using half8 = __attribute__((ext_vector_type(8))) _Float16;
using f32x4 = __attribute__((ext_vector_type(4))) float;
typedef unsigned long long u64;

static constexpr int TT  = 2048;   // time steps
static constexpr int NB  = 16;     // batch
static constexpr int SS  = 512;    // state dim
static constexpr int NWG = 8;      // WGs per protocol group (64 cols each)
static constexpr int NT  = 2;      // teams (8 batches each)
static constexpr int NBT = 8;      // batches per team
static constexpr int HSLOT = 8;    // hmail ring depth

// -------------------- transpose + fp32->f16 (512x512): out[c][r] = in[r][c] --------------------
__global__ __launch_bounds__(256) void tcvt_kernel(const float* __restrict__ in,
                                                   _Float16* __restrict__ out) {
    __shared__ float tile[32][33];
    int bid = blockIdx.x;
    int rb = (bid >> 4) * 32, cb = (bid & 15) * 32;
    int tx = threadIdx.x & 31, ty = threadIdx.x >> 5;
    for (int rr = ty; rr < 32; rr += 8)
        tile[rr][tx] = in[(size_t)(rb + rr) * SS + cb + tx];
    __syncthreads();
    for (int rr = ty; rr < 32; rr += 8)
        out[(size_t)(cb + rr) * SS + rb + tx] = (_Float16)tile[tx][rr];
}

// -------------------- pack weights for scan: out[kk][c][8] f16 from fp32 [k][c] ----------------
__global__ __launch_bounds__(256) void wpack_kernel(const float* __restrict__ in,
                                                    _Float16* __restrict__ out) {
    int idx = blockIdx.x * blockDim.x + threadIdx.x;   // 64*512 = 32768
    int kk = idx >> 9, c = idx & 511;
    half8 v;
    #pragma unroll
    for (int j = 0; j < 8; ++j) v[j] = (_Float16)in[(size_t)(kk * 8 + j) * SS + c];
    *(half8*)(out + (size_t)idx * 8) = v;
}

// -------------------- W = C0 @ B1 (512x512x512 fp32) --------------------
__global__ __launch_bounds__(256) void wmm_kernel(const float* __restrict__ C0,
                                                  const float* __restrict__ B1,
                                                  float* __restrict__ W) {
    int k = blockIdx.x;
    int tid = threadIdx.x;
    const float* crow = C0 + (size_t)k * SS;
    float s0 = 0.f, s1 = 0.f;
    for (int m = 0; m < SS; ++m) {
        float cv = crow[m];
        s0 += cv * B1[(size_t)m * SS + tid];
        s1 += cv * B1[(size_t)m * SS + tid + 256];
    }
    W[(size_t)k * SS + tid] = s0;
    W[(size_t)k * SS + tid + 256] = s1;
}

// -------------------- zero flags (every launch: graph replay safe) -----------------------------
__global__ __launch_bounds__(512) void zinit_kernel(unsigned* __restrict__ p, int n) {
    int i = blockIdx.x * blockDim.x + threadIdx.x;
    if (i < n) p[i] = 0u;
}

// -------------------- big GEMM: M=32768(b*2048+t), N=512, K=512 --------------------
template <int ALAY, int MODE>
__global__ __launch_bounds__(256) void gemm_kernel(const void* __restrict__ Aptr,
                                                   const _Float16* __restrict__ BT,
                                                   void* __restrict__ Outp) {
    int lane = threadIdx.x & 63;
    int wv   = threadIdx.x >> 6;
    int wid  = blockIdx.x * 4 + wv;
    int mt   = wid >> 3;
    int nb   = (wid & 7) * 64;
    int mbase = mt * 16;
    int lo = lane & 15, q = lane >> 4;

    f32x4 acc[4] = {{0,0,0,0},{0,0,0,0},{0,0,0,0},{0,0,0,0}};

    const float*    Af = (const float*)Aptr;
    const _Float16* Ah = (const _Float16*)Aptr;
    size_t arow = (size_t)(mbase + lo) * SS;

    #pragma unroll 2
    for (int kk = 0; kk < 16; ++kk) {
        int koff = kk * 32 + q * 8;
        half8 af;
        if (ALAY == 0) {
            const float* ar = Af + arow + koff;
            f32x4 a0 = *(const f32x4*)ar;
            f32x4 a1 = *(const f32x4*)(ar + 4);
            #pragma unroll
            for (int j = 0; j < 4; ++j) { af[j] = (_Float16)a0[j]; af[4 + j] = (_Float16)a1[j]; }
        } else {
            af = *(const half8*)(Ah + arow + koff);
        }
        #pragma unroll
        for (int j = 0; j < 4; ++j) {
            int n = nb + j * 16 + lo;
            half8 bf = *(const half8*)(BT + (size_t)n * SS + koff);
            acc[j] = __builtin_amdgcn_mfma_f32_16x16x32_f16(af, bf, acc[j], 0, 0, 0);
        }
    }

    #pragma unroll
    for (int j = 0; j < 4; ++j) {
        #pragma unroll
        for (int i = 0; i < 4; ++i) {
            int m = mbase + q * 4 + i;
            int n = nb + j * 16 + lo;
            if (MODE == 0) {
                ((_Float16*)Outp)[(size_t)m * SS + n] = (_Float16)acc[j][i];
            } else if (MODE == 1) {
                ((float*)Outp)[(size_t)m * SS + n] = acc[j][i];
            } else {
                int t2 = m & (TT - 1);
                int b2 = m >> 11;                 // T = 2048 = 2^11
                ((_Float16*)Outp)[((size_t)t2 * NB + b2) * SS + n] = (_Float16)acc[j][i];
            }
        }
    }
}

// -------------------- fused two-layer pipelined cooperative scan -------------------------------
// 32 WGs = {layer} x {team} x {8 col-slice WGs}. Each (layer,team) group runs the round-13
// champion protocol (publish z -> vmcnt(0)+barrier -> flag -> parallel 1-word poll -> gather).
// Layer 1 trails layer 0 by ~3 steps: L0 publishes h(t) into an 8-slot LLC ring (hmail),
// certified by its flag t+2 (h drains with the next step's vmcnt(0)) + a final flag TT+1.
// L1 stages h0(t+1) into LDS during its step-t tail and computes U1(t) = h0(t) @ W with 16
// extra MFMAs (U1 stays fp32 -- no f16 round-trip). Cross-layer flow control is flags-only:
// L0 polls L1 >= t-7 (ring overwrite guard); L1 polls L0 >= t+3 (h0(t+1) certification).
// Deadlock-free: mutual block needs s < t-4 and t < s+2 (contradiction); equilibrium lead 3
// sits in the [2,8] window with zero waiting.
__global__ __launch_bounds__(512) void scan15_kernel(
        const _Float16* __restrict__ U,      // [T][NB][SS] layer-0 input proj
        const _Float16* __restrict__ PA0,    // packed f16 [kk][c][8]
        const _Float16* __restrict__ PK0,
        const float* __restrict__ ab0, const float* __restrict__ gn0, const float* __restrict__ bt0,
        const _Float16* __restrict__ PA1,
        const _Float16* __restrict__ PK1,
        const _Float16* __restrict__ PW,     // packed (C0@B1)
        const float* __restrict__ ab1, const float* __restrict__ gn1, const float* __restrict__ bt1,
        _Float16* __restrict__ hs1,          // [NB][T][SS] layer-1 history out
        u64*      __restrict__ zmail,        // [4 grp][2 par][8 wg][256] u64
        u64*      __restrict__ smail,        // [4 grp][2 par][8 wg][8] u64
        unsigned* __restrict__ flags,        // [4 grp][8 wg][32]
        _Float16* __restrict__ hmail)        // [2 team][8 slot][8 b][512]
{
    const int layer = blockIdx.x >> 4;
    const int team  = (blockIdx.x >> 3) & 1;
    const int wg    = blockIdx.x & 7;
    const int btm   = team * NBT;
    const int tid   = threadIdx.x;
    const int wv    = tid >> 6;
    const int lane  = tid & 63;
    const int q     = lane >> 4;
    const int r     = lane & 15;

    const _Float16* PA  = layer ? PA1 : PA0;
    const _Float16* PK  = layer ? PK1 : PK0;
    const float*    abp = layer ? ab1 : ab0;
    const float*    gnp = layer ? gn1 : gn0;
    const float*    btp = layer ? bt1 : bt0;

    const int pg = layer * 2 + team;
    u64*      zmailT = zmail + (size_t)pg * (2 * NWG * 256);
    u64*      smailT = smail + (size_t)pg * (2 * NWG * 8);
    unsigned* flagsT = flags + (size_t)pg * (NWG * 32);
    unsigned* flagsO = flags + (size_t)((1 - layer) * 2 + team) * (NWG * 32);
    _Float16* hmailT = hmail + (size_t)team * (HSLOT * NBT * SS);

    __shared__ _Float16 H16[16][520];          // own-layer h (rows 8-15 stay zero)
    __shared__ _Float16 H0[16][520];           // layer-0 h staged for L1 (rows 8-15 zero)
    alignas(16) __shared__ float ZW32[8][64];
    __shared__ float STAT[4][16][2];
    __shared__ float GG[512], BB[512];

    const int ub = tid & 7;             // batch within team
    const int ug = tid >> 3;            // 0..63
    const int uc = ug * 8;              // col start (8 cols/thread)
    const int ow = ug >> 3;             // owning WG of this col slice

    for (int e = tid; e < 16 * 520; e += 512) {
        (&H16[0][0])[e] = (_Float16)0.f;
        (&H0[0][0])[e]  = (_Float16)0.f;
    }
    GG[tid] = gnp[tid];
    BB[tid] = btp[tid];

    const bool mf = (wv < 4);
    const int ccol = wg * 64 + (wv & 3) * 16 + r;
    const float abreg = abp[ccol];

    float hreg[8];
    #pragma unroll
    for (int i = 0; i < 8; ++i) hreg[i] = 0.f;
    float uprev[4] = {0.f, 0.f, 0.f, 0.f};
    float ucur[4]  = {0.f, 0.f, 0.f, 0.f};
    if (layer == 0 && mf && q < 2) {
        #pragma unroll
        for (int i = 0; i < 4; ++i)
            ucur[i] = (float)U[(size_t)(btm + q * 4 + i) * SS + ccol];   // t = 0
    }
    __syncthreads();

    // L1 prologue: wait for h0(0) (certified by L0 flag >= 2), stage into H0
    if (layer == 1) {
        if (wv == 0 && lane < 8) {
            while (__hip_atomic_load(&flagsO[lane * 32], __ATOMIC_RELAXED,
                                     __HIP_MEMORY_SCOPE_AGENT) < 2u) {}
        }
        __syncthreads();
        {
            const u64* hp = (const u64*)(hmailT + ((size_t)0 * NBT + ub) * SS + uc);
            union { u64 u[2]; half8 h; } hv;
            hv.u[0] = __hip_atomic_load(hp + 0, __ATOMIC_RELAXED, __HIP_MEMORY_SCOPE_AGENT);
            hv.u[1] = __hip_atomic_load(hp + 1, __ATOMIC_RELAXED, __HIP_MEMORY_SCOPE_AGENT);
            *(half8*)&H0[ub][uc] = hv.h;
        }
        __syncthreads();
    }

    for (int t = 0; t < TT; ++t) {
        const int par = t & 1;

        if (mf) {
            f32x4 zA = {0.f, 0.f, 0.f, 0.f}, zK = {0.f, 0.f, 0.f, 0.f};
            #pragma unroll
            for (int ks = 0; ks < 16; ++ks) {
                half8 hf = *(const half8*)(&H16[r][ks * 32 + q * 8]);
                half8 wa = *(const half8*)(PA + (((size_t)(ks * 4 + q)) * SS + ccol) * 8);
                half8 wk = *(const half8*)(PK + (((size_t)(ks * 4 + q)) * SS + ccol) * 8);
                zA = __builtin_amdgcn_mfma_f32_16x16x32_f16(hf, wa, zA, 0, 0, 0);
                zK = __builtin_amdgcn_mfma_f32_16x16x32_f16(hf, wk, zK, 0, 0, 0);
            }
            if (layer == 1) {          // U1(t) = h0(t) @ W, same fragment pattern (fp32 result)
                f32x4 ua = {0.f, 0.f, 0.f, 0.f};
                #pragma unroll
                for (int ks = 0; ks < 16; ++ks) {
                    half8 h0f = *(const half8*)(&H0[r][ks * 32 + q * 8]);
                    half8 ww  = *(const half8*)(PW + (((size_t)(ks * 4 + q)) * SS + ccol) * 8);
                    ua = __builtin_amdgcn_mfma_f32_16x16x32_f16(h0f, ww, ua, 0, 0, 0);
                }
                #pragma unroll
                for (int i = 0; i < 4; ++i) ucur[i] = ua[i];
            }

            float z[4];
            #pragma unroll
            for (int i = 0; i < 4; ++i) {
                z[i] = zA[i] + ucur[i] + abreg + zK[i] * uprev[i];
                uprev[i] = ucur[i];
            }
            if (q < 2) {
                #pragma unroll
                for (int i = 0; i < 4; ++i)
                    ZW32[q * 4 + i][(wv & 3) * 16 + r] = z[i];
            }

            float s1[4], s2[4];
            #pragma unroll
            for (int i = 0; i < 4; ++i) { s1[i] = z[i]; s2[i] = z[i] * z[i]; }
            #pragma unroll
            for (int off = 1; off < 16; off <<= 1) {
                #pragma unroll
                for (int i = 0; i < 4; ++i) {
                    s1[i] += __shfl_xor(s1[i], off, 64);
                    s2[i] += __shfl_xor(s2[i], off, 64);
                }
            }
            if (r == 0) {
                #pragma unroll
                for (int i = 0; i < 4; ++i) {
                    STAT[wv][q * 4 + i][0] = s1[i];
                    STAT[wv][q * 4 + i][1] = s2[i];
                }
            }
        }
        __syncthreads();                                   // B1

        if (tid < 256) {
            u64 v = ((const u64*)ZW32)[tid];
            __hip_atomic_store(&zmailT[((size_t)par * NWG + wg) * 256 + tid], v,
                               __ATOMIC_RELAXED, __HIP_MEMORY_SCOPE_AGENT);
        }
        if (wv == 0 && lane < NBT) {
            float S1 = STAT[0][lane][0] + STAT[1][lane][0] + STAT[2][lane][0] + STAT[3][lane][0];
            float S2 = STAT[0][lane][1] + STAT[1][lane][1] + STAT[2][lane][1] + STAT[3][lane][1];
            union { float f[2]; u64 u; } pk;
            pk.f[0] = S1; pk.f[1] = S2;
            __hip_atomic_store(&smailT[((size_t)par * NWG + wg) * 8 + lane], pk.u,
                               __ATOMIC_RELAXED, __HIP_MEMORY_SCOPE_AGENT);
        }
        if (layer == 0 && mf && q < 2) {        // prefetch next-step U under the drain
            const int tn = (t + 1 < TT) ? (t + 1) : t;
            #pragma unroll
            for (int i = 0; i < 4; ++i)
                ucur[i] = (float)U[((size_t)tn * NB + btm + q * 4 + i) * SS + ccol];
        }
        __builtin_amdgcn_s_waitcnt(0);
        __syncthreads();                                   // B2: z (+ prev h) at coherence point

        if (tid == 0)
            __hip_atomic_store(&flagsT[wg * 32], (unsigned)(t + 1),
                               __ATOMIC_RELAXED, __HIP_MEMORY_SCOPE_AGENT);
        if (wv == 0 && lane >= 1 && lane < NWG) {          // own peers
            unsigned* fp = &flagsT[((wg + lane) & (NWG - 1)) * 32];
            while (__hip_atomic_load(fp, __ATOMIC_RELAXED, __HIP_MEMORY_SCOPE_AGENT)
                   < (unsigned)(t + 1)) {}
        }
        if (wv == 0 && lane >= 8 && lane < 16) {           // cross-layer
            unsigned thr;
            if (layer == 0) thr = (t > 7) ? (unsigned)(t - 7) : 0u;      // hmail ring guard
            else            thr = (t + 1 < TT) ? (unsigned)(t + 3) : 0u; // h0(t+1) certified
            if (thr) {
                unsigned* fp = &flagsO[(lane - 8) * 32];
                while (__hip_atomic_load(fp, __ATOMIC_RELAXED, __HIP_MEMORY_SCOPE_AGENT) < thr) {}
            }
        }
        __syncthreads();                                   // B3

        // gather z (batch ub, cols uc..uc+7)
        float zz[8];
        if (ow == wg) {
            #pragma unroll
            for (int i = 0; i < 8; ++i) zz[i] = ZW32[ub][(uc & 63) + i];
        } else {
            union { u64 u[4]; float f[8]; } zu;
            const u64* src = &zmailT[((size_t)par * NWG + ow) * 256 + ub * 32 + ((uc & 63) >> 1)];
            #pragma unroll
            for (int i = 0; i < 4; ++i)
                zu.u[i] = __hip_atomic_load(src + i, __ATOMIC_RELAXED, __HIP_MEMORY_SCOPE_AGENT);
            #pragma unroll
            for (int i = 0; i < 8; ++i) zz[i] = zu.f[i];
        }
        // global LN stats (fixed ascending WG order -> identical bits in every WG)
        float S1 = 0.f, S2 = 0.f;
        #pragma unroll
        for (int i = 0; i < NWG; ++i) {
            union { u64 u; float f[2]; } pk;
            pk.u = __hip_atomic_load(&smailT[((size_t)par * NWG + i) * 8 + ub],
                                     __ATOMIC_RELAXED, __HIP_MEMORY_SCOPE_AGENT);
            S1 += pk.f[0]; S2 += pk.f[1];
        }
        const float mu  = S1 * (1.0f / SS);
        const float var = S2 * (1.0f / SS) - mu * mu;
        const float rs  = rsqrtf(var + 1e-5f);

        // replicated LN + exact GELU + h update (8 elems/thread)
        half8 hh;
        #pragma unroll
        for (int i4 = 0; i4 < 2; ++i4) {
            f32x4 gq = *(const f32x4*)&GG[uc + i4 * 4];
            f32x4 bq = *(const f32x4*)&BB[uc + i4 * 4];
            #pragma unroll
            for (int jj = 0; jj < 4; ++jj) {
                const int e = i4 * 4 + jj;
                float zn = (zz[e] - mu) * rs * gq[jj] + bq[jj];
                float ge = 0.5f * zn * (1.0f + erff(zn * 0.70710678118654752f));
                hreg[e] += ge;
                hh[e] = (_Float16)hreg[e];
            }
        }
        *(half8*)(&H16[ub][uc]) = hh;

        if (layer == 0) {
            if (ow == wg) {                                // publish h(t) into hmail ring
                u64* hp = (u64*)(hmailT + (((size_t)(t & (HSLOT - 1))) * NBT + ub) * SS + uc);
                union { half8 h; u64 u[2]; } hv; hv.h = hh;
                __hip_atomic_store(hp + 0, hv.u[0], __ATOMIC_RELAXED, __HIP_MEMORY_SCOPE_AGENT);
                __hip_atomic_store(hp + 1, hv.u[1], __ATOMIC_RELAXED, __HIP_MEMORY_SCOPE_AGENT);
            }
        } else {
            if (ow == wg)                                  // history out (feeds final GEMM)
                *(half8*)(hs1 + ((size_t)(btm + ub) * TT + t) * SS + uc) = hh;
            if (t + 1 < TT) {                              // stage h0(t+1) for next step
                const u64* hp = (const u64*)(hmailT
                                + (((size_t)((t + 1) & (HSLOT - 1))) * NBT + ub) * SS + uc);
                union { u64 u[2]; half8 h; } hv;
                hv.u[0] = __hip_atomic_load(hp + 0, __ATOMIC_RELAXED, __HIP_MEMORY_SCOPE_AGENT);
                hv.u[1] = __hip_atomic_load(hp + 1, __ATOMIC_RELAXED, __HIP_MEMORY_SCOPE_AGENT);
                *(half8*)&H0[ub][uc] = hv.h;
            }
        }
        __syncthreads();                                   // B5
    }

    // L0 epilogue: certify the last hmail writes (h0(TT-1)) with a final flag
    if (layer == 0) {
        __builtin_amdgcn_s_waitcnt(0);
        __syncthreads();
        if (tid == 0)
            __hip_atomic_store(&flagsT[wg * 32], (unsigned)(TT + 1),
                               __ATOMIC_RELAXED, __HIP_MEMORY_SCOPE_AGENT);
    }
}

// -------------------- host launch --------------------
extern "C" void kernel_launch(void* const* d_in, const int* in_sizes, int n_in,
                              void* d_out, int out_size, void* d_ws, size_t ws_size,
                              hipStream_t stream) {
    const float* x   = (const float*)d_in[0];
    const float* A0  = (const float*)d_in[1];
    const float* B0  = (const float*)d_in[2];
    const float* C0  = (const float*)d_in[3];
    const float* K0  = (const float*)d_in[4];
    const float* ab0 = (const float*)d_in[5];
    const float* g0  = (const float*)d_in[6];
    const float* bt0 = (const float*)d_in[7];
    const float* A1  = (const float*)d_in[8];
    const float* B1  = (const float*)d_in[9];
    const float* C1  = (const float*)d_in[10];
    const float* K1  = (const float*)d_in[11];
    const float* ab1 = (const float*)d_in[12];
    const float* g1  = (const float*)d_in[13];
    const float* bt1 = (const float*)d_in[14];

    char* ws = (char*)d_ws;
    size_t off = 0;
    auto alloc = [&](size_t bytes) { size_t o = off; off = (off + bytes + 255) & ~(size_t)255; return o; };

    const size_t BUF_BYTES = (size_t)NB * TT * SS * 2;   // 33.5 MB f16
    const size_t WP_BYTES  = (size_t)SS * SS * 2;        // 512 KB f16

    _Float16* U0  = (_Float16*)(ws + alloc(BUF_BYTES));  // [t][b][c]
    _Float16* hs1 = (_Float16*)(ws + alloc(BUF_BYTES));  // [b][t][c]
    _Float16* B0T = (_Float16*)(ws + alloc(WP_BYTES));
    _Float16* C1T = (_Float16*)(ws + alloc(WP_BYTES));
    _Float16* PA0 = (_Float16*)(ws + alloc(WP_BYTES));   // packed [kk][c][8]
    _Float16* PK0 = (_Float16*)(ws + alloc(WP_BYTES));
    _Float16* PA1 = (_Float16*)(ws + alloc(WP_BYTES));
    _Float16* PK1 = (_Float16*)(ws + alloc(WP_BYTES));
    _Float16* PW  = (_Float16*)(ws + alloc(WP_BYTES));
    float*    Wf  = (float*)(ws + alloc((size_t)SS * SS * 4));
    u64*      zmail = (u64*)(ws + alloc((size_t)4 * 2 * NWG * 256 * 8));   // 128 KB
    u64*      smail = (u64*)(ws + alloc((size_t)4 * 2 * NWG * 8 * 8));     // 4 KB
    unsigned* flags = (unsigned*)(ws + alloc((size_t)4 * NWG * 32 * 4));   // 4 KB
    _Float16* hmail = (_Float16*)(ws + alloc((size_t)NT * HSLOT * NBT * SS * 2)); // 128 KB

    // zero flags (stream-ordered; graph-replay safe)
    zinit_kernel<<<2, 512, 0, stream>>>(flags, 4 * NWG * 32);

    // weight preps
    tcvt_kernel<<<256, 256, 0, stream>>>(B0, B0T);
    tcvt_kernel<<<256, 256, 0, stream>>>(C1, C1T);
    wmm_kernel<<<512, 256, 0, stream>>>(C0, B1, Wf);     // W = C0 @ B1 (layer-fold)
    wpack_kernel<<<128, 256, 0, stream>>>(A0, PA0);
    wpack_kernel<<<128, 256, 0, stream>>>(K0, PK0);
    wpack_kernel<<<128, 256, 0, stream>>>(A1, PA1);
    wpack_kernel<<<128, 256, 0, stream>>>(K1, PK1);
    wpack_kernel<<<128, 256, 0, stream>>>(Wf, PW);

    // U0 = x @ B0, scan layout [t][b][c]
    gemm_kernel<0, 2><<<4096, 256, 0, stream>>>((const void*)x, B0T, (void*)U0);

    // fused two-layer pipelined scan: 32 WGs = {L0,L1} x {team0,team1} x 8
    scan15_kernel<<<32, 512, 0, stream>>>(U0, PA0, PK0, ab0, g0, bt0,
                                          PA1, PK1, PW, ab1, g1, bt1,
                                          hs1, zmail, smail, flags, hmail);

    // out = hs1 @ C1 (fp32 [b][t][c])
    gemm_kernel<1, 1><<<4096, 256, 0, stream>>>((const void*)hs1, C1T, d_out);
}